// Round 1
// baseline (9571.540 us; speedup 1.0000x reference)
//
#include <hip/hip_runtime.h>
#include <math.h>

#define BS 256
#define NN 2048
#define KK 64
#define KP1 65
#define NTHREADS 512
#define RPT 4              // rows per thread = NN / NTHREADS
#define MAX_ITER 200

// ---- monotone float<->uint encoding for atomic min/max ----
__device__ __forceinline__ unsigned enc_f32(float f) {
    unsigned b = __float_as_uint(f);
    return b ^ (unsigned)(((int)b >> 31) | (int)0x80000000);
}
__device__ __forceinline__ float dec_f32(unsigned e) {
    unsigned b = (e & 0x80000000u) ? (e & 0x7FFFFFFFu) : ~e;
    return __uint_as_float(b);
}

// ---- kernel 1: global min/max of scores (ignoring -inf for min), count -inf ----
__global__ void minmax_kernel(const float* __restrict__ s,
                              unsigned* __restrict__ maxenc,
                              unsigned* __restrict__ minenc,
                              unsigned* __restrict__ infc) {
    int tid = blockIdx.x * blockDim.x + threadIdx.x;
    int stride = gridDim.x * blockDim.x;
    float mx = -INFINITY, mn = INFINITY;
    unsigned cnt = 0;
    for (int i = tid; i < BS * NN; i += stride) {
        float v = s[i];
        if (isinf(v) && v < 0.0f) cnt++;
        else { mx = fmaxf(mx, v); mn = fminf(mn, v); }
    }
    for (int off = 32; off > 0; off >>= 1) {
        mx = fmaxf(mx, __shfl_down(mx, off));
        mn = fminf(mn, __shfl_down(mn, off));
        cnt += __shfl_down(cnt, off);
    }
    __shared__ float smx[8], smn[8];
    __shared__ unsigned scnt[8];
    int wid = threadIdx.x >> 6, lane = threadIdx.x & 63;
    if (lane == 0) { smx[wid] = mx; smn[wid] = mn; scnt[wid] = cnt; }
    __syncthreads();
    if (threadIdx.x == 0) {
        int nw = blockDim.x >> 6;
        for (int w = 1; w < nw; w++) { mx = fmaxf(mx, smx[w]); mn = fminf(mn, smn[w]); cnt += scnt[w]; }
        atomicMax(maxenc, enc_f32(mx));
        atomicMin(minenc, enc_f32(mn));
        if (cnt) atomicAdd(infc, cnt);
    }
}

// ---- kernel 2: per-batch sort + tau + Gamma0 sums + 200-iter Sinkhorn + outputs ----
__global__ __launch_bounds__(NTHREADS, 2)
void sink_main(const float* __restrict__ scores, const float* __restrict__ W,
               float* __restrict__ out,
               const unsigned* __restrict__ maxenc, const unsigned* __restrict__ minenc,
               const unsigned* __restrict__ infc, double* __restrict__ norm_acc)
{
    const int tid = threadIdx.x;
    const int b = blockIdx.x;

    __shared__ float ss[NN];                                    // filled scores
    __shared__ float srt[NN];                                   // sort buffer
    __shared__ float v_sh[68] __attribute__((aligned(16)));     // v (65 used)
    __shared__ float vprev_sh[68];                              // v_{t-1} (for final u)
    __shared__ float slab[2][32 * KP1] __attribute__((aligned(16))); // colsum partials
    __shared__ double red_sh[NTHREADS];
    __shared__ float recS_sh[KK];
    __shared__ float topk_sh[KK];

    const float LOG2E  = 1.4426950408889634f;
    const float inv_n  = 1.0f / 2048.0f;         // exact
    const float nu_last = 1984.0f / 2048.0f;     // exact

    // global scalars
    float smax = dec_f32(*maxenc);
    float smin = dec_f32(*minenc);
    unsigned icnt = *infc;
    float filled = smin - (smax - smin);
    float slo = (icnt > 0) ? filled : smin;
    // C.max() is attained at an extreme s with anchor 0 or 64 (convexity)
    float cA = slo * slo, cB = (slo - 64.0f) * (slo - 64.0f);
    float cC = smax * smax, cD = (smax - 64.0f) * (smax - 64.0f);
    float Cmax = fmaxf(fmaxf(cA, cB), fmaxf(cC, cD));
    float negc2 = -(10.0f * LOG2E) / Cmax;       // exp(-C/Cmax/0.1) == exp2(d*d*negc2)

    // load + -inf fill
    for (int i = tid; i < NN; i += NTHREADS) {
        float v = scores[(size_t)b * NN + i];
        if (isinf(v) && v < 0.0f) v = filled;
        ss[i] = v; srt[i] = v;
    }
    __syncthreads();

    // bitonic sort (ascending), 1024 pairs/stage over 512 threads
    for (int size = 2; size <= NN; size <<= 1) {
        for (int stride = size >> 1; stride > 0; stride >>= 1) {
            #pragma unroll
            for (int pp = 0; pp < (NN / 2) / NTHREADS; pp++) {
                int p = tid + pp * NTHREADS;
                int lo = ((p & ~(stride - 1)) << 1) | (p & (stride - 1));
                int hi = lo + stride;
                bool up = ((lo & size) == 0);
                float x = srt[lo], y = srt[hi];
                if ((x > y) == up) { srt[lo] = y; srt[hi] = x; }
            }
            __syncthreads();
        }
    }

    // topk (descending) from sorted
    for (int k = tid; k < KK; k += NTHREADS) topk_sh[k] = srt[NN - 1 - k];

    // tau = sum(sorted * W), fp64 accumulate
    double tp = 0.0;
    for (int i = tid; i < NN; i += NTHREADS) tp += (double)srt[i] * (double)W[i];
    red_sh[tid] = tp;
    __syncthreads();
    for (int s2 = NTHREADS / 2; s2 > 0; s2 >>= 1) {
        if (tid < s2) red_sh[tid] += red_sh[tid + s2];
        __syncthreads();
    }
    float tau = (float)red_sh[0];
    float lt = LOG2E / tau;                      // sigma = 1/(1+exp2(|d|*lt))

    // init v, zero both slabs
    for (int j = tid; j < KP1; j += NTHREADS) v_sh[j] = 1.0f / 65.0f;
    for (int q = tid; q < 2 * 32 * KP1; q += NTHREADS) ((float*)slab)[q] = 0.0f;
    __syncthreads();

    const int g32 = tid & 31;

    // Gamma0 column sums S_k (into slab[1]; slab[1] gets re-zeroed by iter t=0)
    {
        float part[KK];
        #pragma unroll
        for (int k = 0; k < KK; k++) part[k] = 0.0f;
        for (int r = 0; r < RPT; r++) {
            float si = ss[tid + r * NTHREADS];
            #pragma unroll
            for (int k = 0; k < KK; k++) {
                float d = fabsf(topk_sh[k] - si);
                float e = __builtin_amdgcn_exp2f(d * lt);
                float sg = 1.0f / (1.0f + e) + 1e-20f;
                part[k] += sg;
            }
        }
        #pragma unroll
        for (int k = 0; k < KK; k++) atomicAdd(&slab[1][g32 * KP1 + k], part[k]);
    }
    __syncthreads();
    if (tid < KK) {
        float sum = 0.0f;
        #pragma unroll
        for (int g = 0; g < 32; g++) sum += slab[1][g * KP1 + tid];
        recS_sh[tid] = 1.0f / sum;
    }
    __syncthreads();

    // ---- Sinkhorn: 200 iterations ----
    float vloc[KP1], cp[KP1], G[KP1];

    for (int t = 0; t < MAX_ITER; t++) {
        float* sl  = &slab[t & 1][0];
        float* slz = &slab[(t + 1) & 1][0];
        #pragma unroll
        for (int q = 0; q < 16; q++) {
            float4 vv = ((const float4*)v_sh)[q];
            vloc[4 * q + 0] = vv.x; vloc[4 * q + 1] = vv.y;
            vloc[4 * q + 2] = vv.z; vloc[4 * q + 3] = vv.w;
        }
        vloc[64] = v_sh[64];
        #pragma unroll
        for (int j = 0; j < KP1; j++) cp[j] = 0.0f;
        // zero next-iteration slab (its readers finished before the entry barrier)
        for (int q = tid; q < 32 * KP1; q += NTHREADS) slz[q] = 0.0f;

        for (int r = 0; r < RPT; r++) {
            float si = ss[tid + r * NTHREADS];
            float a0 = 0.f, a1 = 0.f, a2 = 0.f, a3 = 0.f;
            #pragma unroll
            for (int j = 0; j < KP1; j++) {
                float d = si - (float)(KK - j);          // exact anchor constants
                float g = __builtin_amdgcn_exp2f(d * d * negc2);
                G[j] = g;
                float vj = vloc[j];
                if ((j & 3) == 0)      a0 = fmaf(g, vj, a0);
                else if ((j & 3) == 1) a1 = fmaf(g, vj, a1);
                else if ((j & 3) == 2) a2 = fmaf(g, vj, a2);
                else                   a3 = fmaf(g, vj, a3);
            }
            float rowsum = (a0 + a1) + (a2 + a3);
            float u = inv_n / rowsum;                    // IEEE div, matches ref
            #pragma unroll
            for (int j = 0; j < KP1; j++) cp[j] = fmaf(G[j], u, cp[j]);
        }
        #pragma unroll
        for (int j = 0; j < KP1; j++) atomicAdd(&sl[g32 * KP1 + j], cp[j]);
        __syncthreads();
        if (tid < KP1) {
            float cs = 0.0f;
            #pragma unroll
            for (int g = 0; g < 32; g++) cs += sl[g * KP1 + tid];
            float nuj = (tid == KK) ? nu_last : inv_n;
            vprev_sh[tid] = v_sh[tid];                   // keep v_{199} for final u
            v_sh[tid] = nuj / cs;
        }
        __syncthreads();
    }

    // ---- final: Gamma = u*G*v, A = Gamma[:, :, :K]*n, norm vs Gamma0 ----
    float vp[KP1];
    #pragma unroll
    for (int j = 0; j < KP1; j++) { vloc[j] = v_sh[j]; vp[j] = vprev_sh[j]; }

    double npart = 0.0;
    for (int r = 0; r < RPT; r++) {
        int i = tid + r * NTHREADS;
        float si = ss[i];
        float a0 = 0.f, a1 = 0.f, a2 = 0.f, a3 = 0.f;
        #pragma unroll
        for (int j = 0; j < KP1; j++) {
            float d = si - (float)(KK - j);
            float g = __builtin_amdgcn_exp2f(d * d * negc2);
            G[j] = g;
            float vj = vp[j];
            if ((j & 3) == 0)      a0 = fmaf(g, vj, a0);
            else if ((j & 3) == 1) a1 = fmaf(g, vj, a1);
            else if ((j & 3) == 2) a2 = fmaf(g, vj, a2);
            else                   a3 = fmaf(g, vj, a3);
        }
        float rowsum = (a0 + a1) + (a2 + a3);
        float u = inv_n / rowsum;                        // identical to iter-200 u

        float g0sum = 0.0f;
        float* orow = out + ((size_t)b * NN + i) * KK;
        #pragma unroll
        for (int q = 0; q < 16; q++) {
            float4 o;
            float gm, dd, e, sg, g0, df;
            #define DO_K(kk_, fld) { const int k = 4 * q + kk_;            \
                gm = (u * G[k]) * vloc[k];                                 \
                dd = fabsf(topk_sh[k] - si);                               \
                e  = __builtin_amdgcn_exp2f(dd * lt);                      \
                sg = 1.0f / (1.0f + e) + 1e-20f;                           \
                g0 = (sg * recS_sh[k]) * inv_n;                            \
                g0sum += g0;                                               \
                df = gm - g0; npart += (double)df * (double)df;            \
                o.fld = gm * 2048.0f; }
            DO_K(0, x) DO_K(1, y) DO_K(2, z) DO_K(3, w)
            #undef DO_K
            ((float4*)orow)[q] = o;
        }
        float last = inv_n - g0sum;
        last = fminf(fmaxf(last, 1e-20f), 1.0f);         // clip(.,1e-20,1-1e-20)
        float gm64 = (u * G[64]) * vloc[64];
        float df = gm64 - last;
        npart += (double)df * (double)df;
    }

    __syncthreads();
    red_sh[tid] = npart;
    __syncthreads();
    for (int s2 = NTHREADS / 2; s2 > 0; s2 >>= 1) {
        if (tid < s2) red_sh[tid] += red_sh[tid + s2];
        __syncthreads();
    }
    if (tid == 0) atomicAdd(norm_acc, red_sh[0]);
}

// ---- kernel 3: finalize norm ----
__global__ void finalize_kernel(const double* __restrict__ norm_acc, float* __restrict__ out) {
    if (threadIdx.x == 0 && blockIdx.x == 0)
        out[(size_t)BS * NN * KK] = (float)sqrt(*norm_acc);
}

extern "C" void kernel_launch(void* const* d_in, const int* in_sizes, int n_in,
                              void* d_out, int out_size, void* d_ws, size_t ws_size,
                              hipStream_t stream) {
    const float* scores = (const float*)d_in[0];
    const float* W = (const float*)d_in[1];
    float* out = (float*)d_out;

    // ws layout: [0..3] max_enc(init 0), [4..7] inf_count(init 0),
    //            [8..15] norm_acc double(init 0), [16..19] min_enc(init 0xFFFFFFFF)
    unsigned* maxenc = (unsigned*)d_ws;
    unsigned* infc   = maxenc + 1;
    double*  nacc    = (double*)((char*)d_ws + 8);
    unsigned* minenc = (unsigned*)((char*)d_ws + 16);

    hipMemsetAsync(d_ws, 0, 16, stream);
    hipMemsetAsync((char*)d_ws + 16, 0xFF, 4, stream);

    hipLaunchKernelGGL(minmax_kernel, dim3(256), dim3(256), 0, stream,
                       scores, maxenc, minenc, infc);
    hipLaunchKernelGGL(sink_main, dim3(BS), dim3(NTHREADS), 0, stream,
                       scores, W, out, maxenc, minenc, infc, nacc);
    hipLaunchKernelGGL(finalize_kernel, dim3(1), dim3(64), 0, stream, nacc, out);
}